// Round 1
// baseline (68.843 us; speedup 1.0000x reference)
//
#include <hip/hip_runtime.h>

// HSMNet feature_vol + channel-sum + softmax + disparity regression, fused.
// Shapes fixed by setup_inputs(): B=2, C=32, H=96, W=160, maxdisp=384 -> D=48.
// out[b,h,w] = sum_d softmax_d( -(sum_c |ref[b,c,h,w]-tgt[b,c,h,w-d]|) ) * 8d,
// with score := 0 exactly when w < d (reference semantics: cost masked to 0).

#define BB   2
#define CC   32
#define HH   96
#define WW   160
#define DD   48
#define TILE 32      // output columns per block
#define NT   5       // tiles per row (WW / TILE)
#define PARTS 8      // d-parts per column
#define DPP  6       // d values per part (PARTS*DPP == DD)
#define TGTC 80      // staged tgt cols: w0-48 .. w0+31
#define STR  33      // LDS column stride (pad -> bank (col+c)%32, conflict-free)

__global__ __launch_bounds__(256, 4)
void hsm_disp_kernel(const float* __restrict__ ref,
                     const float* __restrict__ tgt,
                     float* __restrict__ out)
{
    __shared__ float tgt_l[TGTC * STR];
    __shared__ float ref_l[TILE * STR];
    __shared__ float pm [PARTS * TILE];
    __shared__ float ps [PARTS * TILE];
    __shared__ float pws[PARTS * TILE];

    // Bijective XCD-aware swizzle: grid 960 = 8 XCDs * 120 contiguous chunks.
    int bx = blockIdx.x;
    int wg = (bx & 7) * 120 + (bx >> 3);

    int t  = wg % NT;          // w-tile index
    int bh = wg / NT;          // b*HH + h
    int w0 = t * TILE;

    const size_t cstride = (size_t)HH * WW;            // per-channel stride
    const size_t base    = (size_t)(bh / HH) * CC * cstride + (size_t)(bh % HH) * WW;

    // ---- stage tgt window [w0-48, w0+31] transposed into LDS ----
    for (int i = threadIdx.x; i < TGTC * CC; i += 256) {
        int c  = i / TGTC;
        int ct = i - c * TGTC;
        int gc = w0 - 48 + ct;                         // global column
        float v = 0.0f;
        if (gc >= 0) v = tgt[base + (size_t)c * cstride + gc];  // gc<=159 always
        tgt_l[ct * STR + c] = v;
    }
    // ---- stage ref tile [w0, w0+31] transposed ----
    for (int i = threadIdx.x; i < TILE * CC; i += 256) {
        int c  = i >> 5;
        int cl = i & 31;
        ref_l[cl * STR + c] = ref[base + (size_t)c * cstride + (w0 + cl)];
    }
    __syncthreads();

    const int cl = threadIdx.x & 31;   // column within tile
    const int p  = threadIdx.x >> 5;   // d-part: d in [p*DPP, p*DPP+DPP)

    // ref column into registers (reused for 6 d values)
    float r[CC];
    #pragma unroll
    for (int c = 0; c < CC; ++c) r[c] = ref_l[cl * STR + c];

    float sc[DPP];
    #pragma unroll
    for (int j = 0; j < DPP; ++j) {
        int d  = p * DPP + j;
        int ct = cl - d + 48;                          // in [1, 79]
        const float* tl = &tgt_l[ct * STR];
        float acc = 0.0f;
        #pragma unroll
        for (int c = 0; c < CC; ++c)
            acc += fabsf(r[c] - tl[c]);
        // reference: cost masked to 0 where w < d  ->  score = 0 (not -inf)
        sc[j] = ((w0 + cl) >= d) ? -acc : 0.0f;
    }

    // partial softmax stats over this part's 6 d values
    float m = sc[0];
    #pragma unroll
    for (int j = 1; j < DPP; ++j) m = fmaxf(m, sc[j]);
    float s = 0.0f, ws = 0.0f;
    #pragma unroll
    for (int j = 0; j < DPP; ++j) {
        float e = __expf(sc[j] - m);
        s  += e;
        ws += e * (float)((p * DPP + j) * 8);
    }
    pm [p * TILE + cl] = m;
    ps [p * TILE + cl] = s;
    pws[p * TILE + cl] = ws;
    __syncthreads();

    // merge 8 partials per column, write prediction
    if (threadIdx.x < TILE) {
        float M = pm[cl];
        #pragma unroll
        for (int q = 1; q < PARTS; ++q) M = fmaxf(M, pm[q * TILE + cl]);
        float S = 0.0f, WS = 0.0f;
        #pragma unroll
        for (int q = 0; q < PARTS; ++q) {
            float f = __expf(pm[q * TILE + cl] - M);
            S  += ps [q * TILE + cl] * f;
            WS += pws[q * TILE + cl] * f;
        }
        out[(size_t)bh * WW + w0 + cl] = WS / S;
    }
}

extern "C" void kernel_launch(void* const* d_in, const int* in_sizes, int n_in,
                              void* d_out, int out_size, void* d_ws, size_t ws_size,
                              hipStream_t stream) {
    const float* left  = (const float*)d_in[0];   // ref
    const float* right = (const float*)d_in[1];   // tgt
    float* out = (float*)d_out;
    (void)in_sizes; (void)n_in; (void)out_size; (void)d_ws; (void)ws_size;

    hsm_disp_kernel<<<dim3(BB * HH * NT), dim3(256), 0, stream>>>(left, right, out);
}

// Round 11
// 62.940 us; speedup vs baseline: 1.0938x; 1.0938x over previous
//
#include <hip/hip_runtime.h>

// HSMNet feature_vol + channel-sum + softmax + disparity regression, fused.
// B=2, C=32, H=96, W=160, D=48. out[b,h,w] = sum_d softmax_d(score)*8d,
// score(w,d) = -(sum_c |ref[c,w]-tgt[c,w-d]|) for w>=d, else exactly 0.
//
// LDS layout [col][c] with STR=36 floats (144B): column starts 16B-aligned so
// the compute phase reads ref/tgt channels as ds_read_b128 (85 B/cyc vs 44 for
// b32). Bank base = (4*ct + c) % 32 -> b128 octet phases cover all 32 banks.

#define CCH  32
#define HH   96
#define WW   160
#define DD   48
#define TILE 32      // output columns per block
#define NT   5       // WW / TILE
#define PARTS 16     // d-parts per column
#define DPP  3       // d per part
#define WIN  80      // staged tgt cols: w0-48 .. w0+31
#define STR  36      // floats per column: 16B-aligned, bank-rotating
#define NBLK (2 * HH * NT)   // 960

__global__ __launch_bounds__(512, 4)
void hsm_disp_kernel(const float* __restrict__ refp,
                     const float* __restrict__ tgtp,
                     float* __restrict__ out)
{
    __shared__ float tgt_l[WIN * STR];    // [col][c], c contiguous
    __shared__ float ref_l[TILE * STR];
    __shared__ float pm [PARTS * TILE];
    __shared__ float ps [PARTS * TILE];
    __shared__ float pws[PARTS * TILE];

    // Bijective XCD-aware swizzle: 960 = 8 XCDs * 120 chunks.
    int bx = blockIdx.x;
    int wg = (bx & 7) * (NBLK / 8) + (bx >> 3);

    int t  = wg % NT;
    int bh = wg / NT;
    int w0 = t * TILE;

    const size_t cs   = (size_t)HH * WW;
    const size_t base = (size_t)(bh / HH) * CCH * cs + (size_t)(bh % HH) * WW;

    const int tid = threadIdx.x;

    // ---- staging: coalesced b32 loads, ALL issued before any LDS store ----
    // tgt: 80 cols * 32 c = 2560 = 5*512 ; ref: 32*32 = 1024 = 2*512.
    float tv[5]; int tct[5], tcc[5];
    #pragma unroll
    for (int k = 0; k < 5; ++k) {
        int i  = tid + k * 512;
        int c  = i / WIN;
        int ct = i - c * WIN;
        int gc = w0 - 48 + ct;                  // global col, may be < 0
        tct[k] = ct; tcc[k] = c;
        tv[k] = (gc >= 0) ? tgtp[base + (size_t)c * cs + gc] : 0.0f;
    }
    float rv2[2]; int rct[2], rcc[2];
    #pragma unroll
    for (int k = 0; k < 2; ++k) {
        int i  = tid + k * 512;
        int c  = i >> 5;
        int ct = i & 31;
        rct[k] = ct; rcc[k] = c;
        rv2[k] = refp[base + (size_t)c * cs + (w0 + ct)];
    }
    #pragma unroll
    for (int k = 0; k < 5; ++k) tgt_l[tct[k] * STR + tcc[k]] = tv[k];
    #pragma unroll
    for (int k = 0; k < 2; ++k) ref_l[rct[k] * STR + rcc[k]] = rv2[k];
    __syncthreads();

    // ---- compute: thread = (col cl, part p), 3 d's per part, b128 reads ----
    const int cl = tid & 31;
    const int p  = tid >> 5;          // 0..15
    const int d0 = p * DPP;
    const int w  = w0 + cl;

    const int ct0 = cl - d0 + 48;     // stream 0 column; ct0-2 >= 1
    const float4* tq0 = (const float4*)&tgt_l[(ct0    ) * STR];
    const float4* tq1 = (const float4*)&tgt_l[(ct0 - 1) * STR];
    const float4* tq2 = (const float4*)&tgt_l[(ct0 - 2) * STR];
    const float4* rb  = (const float4*)&ref_l[cl * STR];

    float a0 = 0.f, a1 = 0.f, a2 = 0.f;
    #pragma unroll
    for (int cq = 0; cq < CCH / 4; ++cq) {
        float4 rv = rb[cq];
        float4 t0 = tq0[cq];
        float4 t1 = tq1[cq];
        float4 t2 = tq2[cq];
        a0 += fabsf(rv.x - t0.x) + fabsf(rv.y - t0.y)
            + fabsf(rv.z - t0.z) + fabsf(rv.w - t0.w);
        a1 += fabsf(rv.x - t1.x) + fabsf(rv.y - t1.y)
            + fabsf(rv.z - t1.z) + fabsf(rv.w - t1.w);
        a2 += fabsf(rv.x - t2.x) + fabsf(rv.y - t2.y)
            + fabsf(rv.z - t2.z) + fabsf(rv.w - t2.w);
    }
    float s0 = (w >= d0)     ? -a0 : 0.f;   // masked cells: score exactly 0
    float s1 = (w >= d0 + 1) ? -a1 : 0.f;
    float s2 = (w >= d0 + 2) ? -a2 : 0.f;

    // partial softmax stats over this part's 3 d values
    float m  = fmaxf(fmaxf(s0, s1), s2);
    float e0 = __expf(s0 - m), e1 = __expf(s1 - m), e2 = __expf(s2 - m);
    pm [p * TILE + cl] = m;
    ps [p * TILE + cl] = e0 + e1 + e2;
    pws[p * TILE + cl] = e0 * (float)(8 * d0)
                       + e1 * (float)(8 * (d0 + 1))
                       + e2 * (float)(8 * (d0 + 2));
    __syncthreads();

    // ---- merge 16 partials per column ----
    if (tid < TILE) {
        float M = pm[tid];
        #pragma unroll
        for (int q = 1; q < PARTS; ++q) M = fmaxf(M, pm[q * TILE + tid]);
        float S = 0.f, WS = 0.f;
        #pragma unroll
        for (int q = 0; q < PARTS; ++q) {
            float f = __expf(pm[q * TILE + tid] - M);
            S  += ps [q * TILE + tid] * f;
            WS += pws[q * TILE + tid] * f;
        }
        out[(size_t)bh * WW + w0 + tid] = WS / S;
    }
}

extern "C" void kernel_launch(void* const* d_in, const int* in_sizes, int n_in,
                              void* d_out, int out_size, void* d_ws, size_t ws_size,
                              hipStream_t stream) {
    const float* left  = (const float*)d_in[0];   // ref
    const float* right = (const float*)d_in[1];   // tgt
    float* outp = (float*)d_out;
    (void)in_sizes; (void)n_in; (void)out_size; (void)d_ws; (void)ws_size;

    hsm_disp_kernel<<<dim3(NBLK), dim3(512), 0, stream>>>(left, right, outp);
}